// Round 7
// baseline (341.944 us; speedup 1.0000x reference)
//
#include <hip/hip_runtime.h>

// Two-layer bidirectional LSTM, S=512, B=8192, I=3, H=5.
// R23: layer1 gate-per-lane x row-per-quad rewrite. R20/R22 proved
// total time = 512 x per-wave step wall (occupancy-independent); the
// wall was 910cy = 360 issue + 550 stall, stall dominated by the
// ds_bpermute h-broadcast in the recurrence chain. New layout: lane =
// (quad=row, gate); each lane computes its gate for ALL 5 units; gates
// exchanged via quad_perm DPP (VALU pipe, no LDS); cell computed
// redundantly in all 4 lanes -> h in-register everywhere, broadcast
// GONE from the chain. 16 rows/wave (64/64 lanes), grid 1024 = 4
// blocks/CU (LDS 39.9KB), XCD swizzle, no tail. MITM carried verbatim
// (TL=208 LDS stash, 48-step compact 10B/quad spill, full-sector out).
// Layer0 unchanged from R22 (verified; port next round if this works).

constexpr int S_ = 512;
constexpr int B_ = 8192;
constexpr int NROW = 16384;    // 2 dirs * 8192

constexpr int GD1 = 1024;          // layer1 grid: 8 b x 2 dirs per wave
constexpr int TL  = 208;           // phi1 steps resident in LDS

constexpr float L2E  = 1.4426950408889634f;   // log2(e)
constexpr float T2E  = 2.8853900817779268f;   // 2*log2(e)
constexpr float IT2E = 0.34657359027997264f;  // 1/(2*log2(e))

typedef _Float16 v2h __attribute__((ext_vector_type(2)));

__device__ __forceinline__ float dot2h(v2h a, v2h b, float c) {
#if __has_builtin(__builtin_amdgcn_fdot2)
    return __builtin_amdgcn_fdot2(a, b, c, false);
#else
    return fmaf((float)a[0], (float)b[0], fmaf((float)a[1], (float)b[1], c));
#endif
}

__device__ __forceinline__ float rcp_(float x) { return __builtin_amdgcn_rcpf(x); }

__device__ __forceinline__ float exp2_(float x) {
#if __has_builtin(__builtin_amdgcn_exp2f)
    return __builtin_amdgcn_exp2f(x);
#else
    return exp2f(x);
#endif
}

__device__ __forceinline__ void sbar() { __builtin_amdgcn_sched_barrier(0); }

// full-wave backward permute: dst = src[lane bidx/4] (layer0 only)
__device__ __forceinline__ float bperm(int bidx, float v) {
    return __int_as_float(__builtin_amdgcn_ds_bpermute(bidx, __float_as_int(v)));
}

// quad broadcast via DPP: every lane of a quad gets lane L's value
template<int L>
__device__ __forceinline__ float qb(float v) {
    return __int_as_float(__builtin_amdgcn_update_dpp(
        0, __float_as_int(v), L * 0x55, 0xF, 0xF, false));
}

__device__ __forceinline__ unsigned pkh(float a, float b) {
    auto t = __builtin_amdgcn_cvt_pkrtz(a, b);   // __fp16 ext_vector(2)
    unsigned q; __builtin_memcpy(&q, &t, 4); return q;
}

__device__ __forceinline__ unsigned short f2h(float x) {
    _Float16 h = (_Float16)x;                    // RTE
    unsigned short s; __builtin_memcpy(&s, &h, 2); return s;
}

__device__ __forceinline__ float h2f(unsigned short s) {
    _Float16 h; __builtin_memcpy(&h, &s, 2); return (float)h;
}

// bijective chunked XCD swizzle for a 1366-block grid (q=170, rem=6)
__device__ __forceinline__ int xswz1366(int bid) {
    const int xcd = bid & 7, loc = bid >> 3;
    const int base = (xcd < 6) ? xcd * 171 : 1026 + (xcd - 6) * 170;
    return base + loc;
}

// ------- Layer 0: x [S][B][3] f32 -> ws planes [2][S][B] 12B fp16 rows -------
__global__ __launch_bounds__(64) __attribute__((amdgpu_waves_per_eu(1, 2)))
void lstm_layer0(
    const float* __restrict__ x,
    const float* __restrict__ wih_f, const float* __restrict__ whh_f,
    const float* __restrict__ bih_f, const float* __restrict__ bhh_f,
    const float* __restrict__ wih_r, const float* __restrict__ whh_r,
    const float* __restrict__ bih_r, const float* __restrict__ bhh_r,
    unsigned short* __restrict__ ws,
    float* __restrict__ outbase)
{
    const int l64 = threadIdx.x & 63;
    int r = l64 / 5; r = (r > 11) ? 11 : r;     // row-in-wave 0..11
    const int u   = l64 - r * 5;                // 0..4 active (5..8 on idle lanes)
    const int uc  = (u < 5) ? u : 4;
    const int bsw = xswz1366((int)blockIdx.x);
    const int gid = bsw * 12 + r;
    const bool valid = gid < NROW;
    const int dir = (gid >> 13) & 1;
    const int b   = gid & 8191;
    const bool stw = valid && (u < 3);          // per-lane dword row-store
    const bool st  = valid && (u < 5);          // epilogue-store lanes

    int bidx[5];
#pragma unroll
    for (int k = 0; k < 5; k++) bidx[k] = (r * 5 + k) * 4;

    const float* __restrict__ wih = dir ? wih_r : wih_f;
    const float* __restrict__ whh = dir ? whh_r : whh_f;
    const float* __restrict__ bih = dir ? bih_r : bih_f;
    const float* __restrict__ bhh = dir ? bhh_r : bhh_f;

    // 4 gate rows for unit uc: i,f,g,o = rows uc, 5+uc, 10+uc, 15+uc
    const int rows[4] = {uc, 5 + uc, 10 + uc, 15 + uc};
    const float scl[4] = {-L2E, -L2E, T2E, -L2E};
    float WX[4][3], WH[4][5], BS[4];
#pragma unroll
    for (int gi = 0; gi < 4; gi++) {
        const int rr = rows[gi]; const float sc = scl[gi];
#pragma unroll
        for (int i = 0; i < 3; i++) WX[gi][i] = wih[rr * 3 + i] * sc;
#pragma unroll
        for (int k = 0; k < 5; k++) WH[gi][k] = whh[rr * 5 + k] * sc;
        BS[gi] = (bih[rr] + bhh[rr]) * sc;
    }

    float h[5] = {0.f, 0.f, 0.f, 0.f, 0.f};
    float cp = 0.f, hu_last = 0.f;              // cp = c * 2log2e

    const int t0 = dir ? (S_ - 1) : 0;
    const float* xp = x + ((size_t)t0 * B_ + b) * 3;
    unsigned short* wp = ws + (size_t)dir * ((size_t)S_ * B_ * 6)
                            + ((size_t)t0 * B_ + b) * 6;
    const ptrdiff_t xst = dir ? -(ptrdiff_t)3 * B_ : (ptrdiff_t)3 * B_;
    const ptrdiff_t wst = dir ? -(ptrdiff_t)6 * B_ : (ptrdiff_t)6 * B_;

    auto step = [&](const float (&xin)[3], unsigned short* wpp) {
        float a0 = BS[0], a1 = BS[1], a2 = BS[2], a3 = BS[3];
#pragma unroll
        for (int i = 0; i < 3; i++) {
            a0 = fmaf(WX[0][i], xin[i], a0);
            a1 = fmaf(WX[1][i], xin[i], a1);
            a2 = fmaf(WX[2][i], xin[i], a2);
            a3 = fmaf(WX[3][i], xin[i], a3);
        }
#pragma unroll
        for (int k = 0; k < 5; k++) {
            a0 = fmaf(WH[0][k], h[k], a0);
            a1 = fmaf(WH[1][k], h[k], a1);
            a2 = fmaf(WH[2][k], h[k], a2);
            a3 = fmaf(WH[3][k], h[k], a3);
        }
        const float ig = rcp_(1.0f + exp2_(a0));
        const float fg = rcp_(1.0f + exp2_(a1));
        const float g2 = fmaf(-2.0f * T2E, rcp_(1.0f + exp2_(a2)), T2E);
        const float og = rcp_(1.0f + exp2_(a3));
        cp = fmaf(fg, cp, ig * g2);
        const float th = fmaf(-2.0f, rcp_(1.0f + exp2_(cp)), 1.0f);
        const float hu = og * th;
        hu_last = hu;
#pragma unroll
        for (int k = 0; k < 5; k++) h[k] = bperm(bidx[k], hu);
        const unsigned q0 = pkh(h[0], h[1]);
        const unsigned q1 = pkh(h[2], h[3]);
        const unsigned q2 = pkh(h[4], 0.0f);
        unsigned qs = q0;
        qs = (u == 1) ? q1 : qs;
        qs = (u == 2) ? q2 : qs;
        if (stw) ((unsigned*)wpp)[u] = qs;
    };

    auto ld = [&](float (&buf)[3]) {
        __builtin_memcpy(&buf[0], xp, 12);
        xp += xst;
        sbar();
    };

    float x0[3], x1[3], x2[3], x3[3], x4[3], x5[3], x6[3], x7[3];
    ld(x0); ld(x1); ld(x2); ld(x3); ld(x4); ld(x5); ld(x6); ld(x7);

#pragma unroll 1
    for (int s = 0; s < S_ - 8; s += 8) {
        step(x0, wp); wp += wst; ld(x0);
        step(x1, wp); wp += wst; ld(x1);
        step(x2, wp); wp += wst; ld(x2);
        step(x3, wp); wp += wst; ld(x3);
        step(x4, wp); wp += wst; ld(x4);
        step(x5, wp); wp += wst; ld(x5);
        step(x6, wp); wp += wst; ld(x6);
        step(x7, wp); wp += wst; ld(x7);
    }
    step(x0, wp); wp += wst;
    step(x1, wp); wp += wst;
    step(x2, wp); wp += wst;
    step(x3, wp); wp += wst;
    step(x4, wp); wp += wst;
    step(x5, wp); wp += wst;
    step(x6, wp); wp += wst;
    step(x7, wp);

    const size_t OUTE = (size_t)S_ * B_ * 10;
    float* hn = outbase + OUTE + ((size_t)dir * B_ + b) * 5;
    float* cn = hn + (size_t)4 * B_ * 5;
    if (st) { hn[uc] = hu_last; cn[uc] = cp * IT2E; }
}

// ------- Layer 1: gate-per-lane x row-per-quad, MITM -------
// quad q = l64>>2 (0..15): quads 0-7 fwd b=b0+q, 8-15 bwd b=b0+q-8.
// lane g = l64&3 computes gate g (i,f,g,o) for all 5 units of its row.
__global__ __launch_bounds__(64) __attribute__((amdgpu_waves_per_eu(1, 2)))
void lstm_layer1(
    const unsigned short* __restrict__ ws,
    const float* __restrict__ wih_f, const float* __restrict__ whh_f,
    const float* __restrict__ bih_f, const float* __restrict__ bhh_f,
    const float* __restrict__ wih_r, const float* __restrict__ whh_r,
    const float* __restrict__ bih_r, const float* __restrict__ bhh_r,
    float* __restrict__ outbase,
    unsigned short* __restrict__ gtemp)
{
    __shared__ unsigned lt[TL * 48];            // [t][quad][3 dwords] = 39936B

    const int l64 = threadIdx.x & 63;
    const int bid = (int)blockIdx.x;
    const int bsw = (bid & 7) * 128 + (bid >> 3);   // XCD swizzle (1024=8*128)
    const int q   = l64 >> 2;                   // quad/row 0..15
    const int g   = l64 & 3;                    // gate: 0=i 1=f 2=g 3=o
    const int dir = q >> 3;
    const int qm  = q & 7;
    const int b   = bsw * 8 + qm;               // 1024*8 = 8192 exact
    const int pq  = q ^ 8;                      // partner quad (other dir, same b)
    // out col-4/9 value select: lane0 col4 owns h4 when fwd; lane1 col9 when bwd
    const bool c2sel = (g == 0) ? (dir == 0) : (dir == 1);

    const float* __restrict__ wih = dir ? wih_r : wih_f;
    const float* __restrict__ whh = dir ? whh_r : whh_f;
    const float* __restrict__ bih = dir ? bih_r : bih_f;
    const float* __restrict__ bhh = dir ? bhh_r : bhh_f;

    // gate g rows: g*5+u. scaling: i/f/o -> -log2e (sigmoid); g -> 2log2e (tanh)
    const float scl = (g == 2) ? T2E : -L2E;
    const float GM  = (g == 2) ? (-2.0f * T2E) : 1.0f;
    const float GB  = (g == 2) ? T2E : 0.0f;

    v2h  WX[5][6];
    float WH[5][5], BS[5];
#pragma unroll
    for (int u = 0; u < 5; u++) {
        const int rr = g * 5 + u;
#pragma unroll
        for (int p = 0; p < 6; p++) {
            const int i0 = (p < 3) ? 2 * p : 2 * p - 1;   // 0,2,4,5,7,9
            const bool pad = (p == 2) || (p == 5);
            const float w0 = wih[rr * 10 + i0] * scl;
            const float w1 = pad ? 0.f : wih[rr * 10 + i0 + 1] * scl;
            WX[u][p] = (v2h){(_Float16)w0, (_Float16)w1};
        }
#pragma unroll
        for (int k = 0; k < 5; k++) WH[u][k] = whh[rr * 5 + k] * scl;
        BS[u] = (bih[rr] + bhh[rr]) * scl;
    }

    float h[5]  = {0.f, 0.f, 0.f, 0.f, 0.f};
    float cp[5] = {0.f, 0.f, 0.f, 0.f, 0.f};

    const int t0 = dir ? (S_ - 1) : 0;
    const unsigned short* rpf = ws + ((size_t)t0 * B_ + b) * 6;
    const unsigned short* rpb = rpf + (size_t)S_ * B_ * 6;
    const ptrdiff_t rst = dir ? -(ptrdiff_t)6 * B_ : (ptrdiff_t)6 * B_;
    // out: first phase-2 row is s=256 (fwd) / s=255 (bwd)
    float* A  = outbase + ((size_t)(dir ? 255 : 256) * B_ + b) * 10 + g;
    float* A2 = outbase + ((size_t)(dir ? 255 : 256) * B_ + b) * 10 + ((g == 0) ? 4 : 9);
    const ptrdiff_t ost = dir ? -(ptrdiff_t)10 * B_ : (ptrdiff_t)10 * B_;

    auto ld = [&](v2h (&buf)[6]) {
        __builtin_memcpy(&buf[0], rpf, 12);
        __builtin_memcpy(&buf[3], rpb, 12);
        rpf += rst; rpb += rst;
        sbar();
    };
    auto dots = [&](const v2h (&xin)[6], float (&a)[5]) {
#pragma unroll
        for (int u = 0; u < 5; u++) {
            float t = BS[u];
#pragma unroll
            for (int p = 0; p < 6; p++) t = dot2h(xin[p], WX[u][p], t);
            a[u] = t;
        }
    };
    auto finish = [&](float (&a)[5]) {
#pragma unroll
        for (int u = 0; u < 5; u++) {
#pragma unroll
            for (int k = 0; k < 5; k++) a[u] = fmaf(WH[u][k], h[k], a[u]);
        }
        float gv[5];
#pragma unroll
        for (int u = 0; u < 5; u++)
            gv[u] = fmaf(GM, rcp_(1.0f + exp2_(a[u])), GB);
        // quad DPP exchange + redundant cell in all 4 lanes -> h in-register
#pragma unroll
        for (int u = 0; u < 5; u++) {
            const float ig = qb<0>(gv[u]);
            const float fg = qb<1>(gv[u]);
            const float gg = qb<2>(gv[u]);
            const float og = qb<3>(gv[u]);
            cp[u] = fmaf(fg, cp[u], ig * gg);
            const float th = fmaf(-2.0f, rcp_(1.0f + exp2_(cp[u])), 1.0f);
            h[u] = og * th;
        }
    };
    auto hsel = [&]() -> float {    // h[g], g in 0..3 (constant-indexed)
        return (g == 0) ? h[0] : (g == 1) ? h[1] : (g == 2) ? h[2] : h[3];
    };

    // phi1a: stash h into LDS as 3 pkh dwords per quad
    unsigned* ltw = lt + q * 3 + g;             // += 48 dwords/step
    auto s1L = [&](v2h (&xb)[6]) {
        float a[5]; dots(xb, a); ld(xb); finish(a);
        const unsigned p0 = pkh(h[0], h[1]);
        const unsigned p1 = pkh(h[2], h[3]);
        const unsigned p2 = pkh(h[4], 0.0f);
        unsigned qs = (g == 1) ? p1 : p0; qs = (g == 2) ? p2 : qs;
        if (g < 3) *ltw = qs;
        ltw += 48;
    };
    // phi1b: compact global spill, 5 shorts/quad (80 shorts/step-row)
    unsigned short* gsw = gtemp + (size_t)bid * (48 * 80) + q * 5 + g;
    auto s1G = [&](v2h (&xb)[6]) {
        float a[5]; dots(xb, a); ld(xb); finish(a);
        *gsw = f2h(hsel());                     // lane g writes h[g]
        if (g == 0) gsw[4] = f2h(h[4]);
        gsw += 80;
    };
    // phase-2 out store: lane g writes cols {g, g+5}; lanes 0/1 write {4, 9}
    auto outst = [&](float pvg, float pv4) {
        const float hg = hsel();
        A[0] = dir ? pvg : hg;                  // col g   (fwd half, unit g)
        A[5] = dir ? hg : pvg;                  // col g+5 (bwd half, unit g)
        if (g < 2) A2[0] = c2sel ? h[4] : pv4;  // col 4 (lane0) / col 9 (lane1)
        A += ost; A2 += ost;
    };
    const unsigned short* grd = gtemp + (size_t)bid * (48 * 80)
                                      + (size_t)47 * 80 + pq * 5;
    auto s2G = [&](v2h (&xb)[6]) {
        const float pvg = h2f(grd[g]);
        const float pv4 = h2f(grd[4]);
        grd -= 80;
        float a[5]; dots(xb, a); ld(xb); finish(a);
        outst(pvg, pv4);
    };
    const unsigned short* lrd = (const unsigned short*)lt
                              + (size_t)(TL - 1) * 96 + pq * 6;
    auto s2L = [&](v2h (&xb)[6]) {
        const float pvg = h2f(lrd[g]);
        const float pv4 = h2f(lrd[4]);
        lrd -= 96;
        float a[5]; dots(xb, a); ld(xb); finish(a);
        outst(pvg, pv4);
    };
    auto s2Ln = [&](v2h (&xb)[6]) {             // tail: no load
        const float pvg = h2f(lrd[g]);
        const float pv4 = h2f(lrd[4]);
        lrd -= 96;
        float a[5]; dots(xb, a); finish(a);
        outst(pvg, pv4);
    };

    v2h x0[6], x1[6], x2[6], x3[6];
    ld(x0); ld(x1); ld(x2); ld(x3);             // t = 0..3

    // phi1a: t = 0..207 (LDS stash)
#pragma unroll 1
    for (int t = 0; t < TL; t += 4) { s1L(x0); s1L(x1); s1L(x2); s1L(x3); }
    // phi1b: t = 208..255 (global spill rows 0..47)
#pragma unroll 1
    for (int t = TL; t < 256; t += 4) { s1G(x0); s1G(x1); s1G(x2); s1G(x3); }
    // drain: same-wave spill write -> read
    asm volatile("s_waitcnt vmcnt(0)" ::: "memory");
    // phi2a: t = 256..303, partner from spill (row 303-t = tp-208)
#pragma unroll 1
    for (int t = 256; t < 304; t += 4) { s2G(x0); s2G(x1); s2G(x2); s2G(x3); }
    // phi2b: t = 304..507, partner from LDS (row 511-t)
#pragma unroll 1
    for (int t = 304; t < 508; t += 4) { s2L(x0); s2L(x1); s2L(x2); s2L(x3); }
    // tail: t = 508..511
    s2Ln(x0); s2Ln(x1); s2Ln(x2); s2Ln(x3);

    // epilogue: h_n slot (2+dir), c_n
    const size_t OUTE = (size_t)S_ * B_ * 10;
    float* hn = outbase + OUTE + ((size_t)(2 + dir) * B_ + b) * 5;
    float* cn = hn + (size_t)4 * B_ * 5;
    const float hg = hsel();
    const float cg = ((g == 0) ? cp[0] : (g == 1) ? cp[1] :
                      (g == 2) ? cp[2] : cp[3]) * IT2E;
    hn[g] = hg; cn[g] = cg;
    if (g == 0) { hn[4] = h[4]; cn[4] = cp[4] * IT2E; }
}

extern "C" void kernel_launch(void* const* d_in, const int* in_sizes, int n_in,
                              void* d_out, int out_size, void* d_ws, size_t ws_size,
                              hipStream_t stream) {
    const float* x       = (const float*)d_in[0];
    const float* wih_l0  = (const float*)d_in[1];
    const float* whh_l0  = (const float*)d_in[2];
    const float* bih_l0  = (const float*)d_in[3];
    const float* bhh_l0  = (const float*)d_in[4];
    const float* wih_l0r = (const float*)d_in[5];
    const float* whh_l0r = (const float*)d_in[6];
    const float* bih_l0r = (const float*)d_in[7];
    const float* bhh_l0r = (const float*)d_in[8];
    const float* wih_l1  = (const float*)d_in[9];
    const float* whh_l1  = (const float*)d_in[10];
    const float* bih_l1  = (const float*)d_in[11];
    const float* bhh_l1  = (const float*)d_in[12];
    const float* wih_l1r = (const float*)d_in[13];
    const float* whh_l1r = (const float*)d_in[14];
    const float* bih_l1r = (const float*)d_in[15];
    const float* bhh_l1r = (const float*)d_in[16];

    float* out = (float*)d_out;
    unsigned short* ws = (unsigned short*)d_ws;   // 2 planes * S*B*12B = 100.7 MB
    // layer1 spill: 1024 blocks * 48 rows * 80 shorts = 7.9 MB after planes
    unsigned short* gtemp = ws + (size_t)2 * S_ * B_ * 6;

    // layer0: 16384 (dir,row) sequences, 12 per wave -> 1366 single-wave blocks
    dim3 grid0(1366), block(64);
    lstm_layer0<<<grid0, block, 0, stream>>>(x,
        wih_l0, whh_l0, bih_l0, bhh_l0,
        wih_l0r, whh_l0r, bih_l0r, bhh_l0r,
        ws, out);
    // layer1: 8 b x 2 dirs per wave -> 1024 blocks = 4 blocks/CU exactly
    dim3 grid1(GD1);
    lstm_layer1<<<grid1, block, 0, stream>>>(ws,
        wih_l1, whh_l1, bih_l1, bhh_l1,
        wih_l1r, whh_l1r, bih_l1r, bhh_l1r,
        out, gtemp);
}

// Round 8
// 309.890 us; speedup vs baseline: 1.1034x; 1.1034x over previous
//
#include <hip/hip_runtime.h>

// Two-layer bidirectional LSTM, S=512, B=8192, I=3, H=5.
// R24: consolidation + one chain probe.
//  - layer0: XCD swizzle REVERTED (R21->R22 A/B: swizzle cost ~6us on
//    layer0 -- x reads are single-use streaming, no inter-block reuse).
//  - layer1: R22 structure (best measured, 195us) with the phase-2b
//    partner LDS read pipelined ONE STEP AHEAD: ds_read issued after
//    the cell's lgkm-drain point, consumed next step. If the compiler
//    was draining the fresh read inside the bperm lgkmcnt wait, this
//    removes a ~100cy LDS round-trip from the per-step chain.
// Invariant established R19-R23: wall-clock = 512 x per-wave step wall
// (~910cy for layer1, ~535 for layer0); occupancy/rows-per-wave are
// conserved -- only per-step wall reduction helps.
// Carried: unit-per-lane 12 rows/wave (5-lane groups), fp16 ws planes,
// fdot2 x-dots, depth-8 prefetch, MITM TL=208 + 48-step spill ring,
// full-sector out runs, l1 bijective XCD swizzle, waves_per_eu(1,2).

constexpr int S_ = 512;
constexpr int B_ = 8192;
constexpr int NROW = 16384;    // 2 dirs * 8192

constexpr int GD1  = 1366;         // layer1 grid = ceil(8192/6)
constexpr int TL   = 208;          // phi1 steps resident in LDS
constexpr int GSTR = GD1 * 64;     // spill stride per step (shorts)

constexpr float L2E  = 1.4426950408889634f;   // log2(e)
constexpr float T2E  = 2.8853900817779268f;   // 2*log2(e)
constexpr float IT2E = 0.34657359027997264f;  // 1/(2*log2(e))

typedef _Float16 v2h __attribute__((ext_vector_type(2)));

__device__ __forceinline__ float dot2h(v2h a, v2h b, float c) {
#if __has_builtin(__builtin_amdgcn_fdot2)
    return __builtin_amdgcn_fdot2(a, b, c, false);
#else
    return fmaf((float)a[0], (float)b[0], fmaf((float)a[1], (float)b[1], c));
#endif
}

__device__ __forceinline__ float rcp_(float x) { return __builtin_amdgcn_rcpf(x); }

__device__ __forceinline__ float exp2_(float x) {
#if __has_builtin(__builtin_amdgcn_exp2f)
    return __builtin_amdgcn_exp2f(x);
#else
    return exp2f(x);
#endif
}

__device__ __forceinline__ void sbar() { __builtin_amdgcn_sched_barrier(0); }

// full-wave backward permute: dst = src[lane bidx/4]
__device__ __forceinline__ float bperm(int bidx, float v) {
    return __int_as_float(__builtin_amdgcn_ds_bpermute(bidx, __float_as_int(v)));
}

__device__ __forceinline__ unsigned pkh(float a, float b) {
    auto t = __builtin_amdgcn_cvt_pkrtz(a, b);   // __fp16 ext_vector(2)
    unsigned q; __builtin_memcpy(&q, &t, 4); return q;
}

__device__ __forceinline__ unsigned short f2h(float x) {
    _Float16 h = (_Float16)x;                    // RTE
    unsigned short s; __builtin_memcpy(&s, &h, 2); return s;
}

__device__ __forceinline__ float h2f(unsigned short s) {
    _Float16 h; __builtin_memcpy(&h, &s, 2); return (float)h;
}

// bijective chunked XCD swizzle for a 1366-block grid (q=170, rem=6)
__device__ __forceinline__ int xswz1366(int bid) {
    const int xcd = bid & 7, loc = bid >> 3;
    const int base = (xcd < 6) ? xcd * 171 : 1026 + (xcd - 6) * 170;
    return base + loc;
}

// ------- Layer 0: x [S][B][3] f32 -> ws planes [2][S][B] 12B fp16 rows -------
__global__ __launch_bounds__(64) __attribute__((amdgpu_waves_per_eu(1, 2)))
void lstm_layer0(
    const float* __restrict__ x,
    const float* __restrict__ wih_f, const float* __restrict__ whh_f,
    const float* __restrict__ bih_f, const float* __restrict__ bhh_f,
    const float* __restrict__ wih_r, const float* __restrict__ whh_r,
    const float* __restrict__ bih_r, const float* __restrict__ bhh_r,
    unsigned short* __restrict__ ws,
    float* __restrict__ outbase)
{
    const int l64 = threadIdx.x & 63;
    int r = l64 / 5; r = (r > 11) ? 11 : r;     // row-in-wave 0..11
    const int u   = l64 - r * 5;                // 0..4 active (5..8 on idle lanes)
    const int uc  = (u < 5) ? u : 4;
    const int gid = blockIdx.x * 12 + r;        // NO swizzle (R22 A/B: it hurt)
    const bool valid = gid < NROW;
    const int dir = (gid >> 13) & 1;
    const int b   = gid & 8191;
    const bool stw = valid && (u < 3);          // per-lane dword row-store
    const bool st  = valid && (u < 5);          // epilogue-store lanes

    int bidx[5];
#pragma unroll
    for (int k = 0; k < 5; k++) bidx[k] = (r * 5 + k) * 4;

    const float* __restrict__ wih = dir ? wih_r : wih_f;
    const float* __restrict__ whh = dir ? whh_r : whh_f;
    const float* __restrict__ bih = dir ? bih_r : bih_f;
    const float* __restrict__ bhh = dir ? bhh_r : bhh_f;

    // 4 gate rows for unit uc: i,f,g,o = rows uc, 5+uc, 10+uc, 15+uc
    const int rows[4] = {uc, 5 + uc, 10 + uc, 15 + uc};
    const float scl[4] = {-L2E, -L2E, T2E, -L2E};
    float WX[4][3], WH[4][5], BS[4];
#pragma unroll
    for (int gi = 0; gi < 4; gi++) {
        const int rr = rows[gi]; const float sc = scl[gi];
#pragma unroll
        for (int i = 0; i < 3; i++) WX[gi][i] = wih[rr * 3 + i] * sc;
#pragma unroll
        for (int k = 0; k < 5; k++) WH[gi][k] = whh[rr * 5 + k] * sc;
        BS[gi] = (bih[rr] + bhh[rr]) * sc;
    }

    float h[5] = {0.f, 0.f, 0.f, 0.f, 0.f};
    float cp = 0.f, hu_last = 0.f;              // cp = c * 2log2e

    const int t0 = dir ? (S_ - 1) : 0;
    const float* xp = x + ((size_t)t0 * B_ + b) * 3;
    unsigned short* wp = ws + (size_t)dir * ((size_t)S_ * B_ * 6)
                            + ((size_t)t0 * B_ + b) * 6;
    const ptrdiff_t xst = dir ? -(ptrdiff_t)3 * B_ : (ptrdiff_t)3 * B_;
    const ptrdiff_t wst = dir ? -(ptrdiff_t)6 * B_ : (ptrdiff_t)6 * B_;

    auto step = [&](const float (&xin)[3], unsigned short* wpp) {
        float a0 = BS[0], a1 = BS[1], a2 = BS[2], a3 = BS[3];
#pragma unroll
        for (int i = 0; i < 3; i++) {
            a0 = fmaf(WX[0][i], xin[i], a0);
            a1 = fmaf(WX[1][i], xin[i], a1);
            a2 = fmaf(WX[2][i], xin[i], a2);
            a3 = fmaf(WX[3][i], xin[i], a3);
        }
#pragma unroll
        for (int k = 0; k < 5; k++) {
            a0 = fmaf(WH[0][k], h[k], a0);
            a1 = fmaf(WH[1][k], h[k], a1);
            a2 = fmaf(WH[2][k], h[k], a2);
            a3 = fmaf(WH[3][k], h[k], a3);
        }
        const float ig = rcp_(1.0f + exp2_(a0));                       // sigmoid i
        const float fg = rcp_(1.0f + exp2_(a1));                       // sigmoid f
        const float g2 = fmaf(-2.0f * T2E, rcp_(1.0f + exp2_(a2)), T2E); // 2log2e*tanh g
        const float og = rcp_(1.0f + exp2_(a3));                       // sigmoid o
        cp = fmaf(fg, cp, ig * g2);
        const float th = fmaf(-2.0f, rcp_(1.0f + exp2_(cp)), 1.0f);
        const float hu = og * th;
        hu_last = hu;
#pragma unroll
        for (int k = 0; k < 5; k++) h[k] = bperm(bidx[k], hu);
        // pack + per-lane dword store: lane u (<3) writes dword u of the row
        const unsigned q0 = pkh(h[0], h[1]);
        const unsigned q1 = pkh(h[2], h[3]);
        const unsigned q2 = pkh(h[4], 0.0f);
        unsigned qs = q0;
        qs = (u == 1) ? q1 : qs;
        qs = (u == 2) ? q2 : qs;
        if (stw) ((unsigned*)wpp)[u] = qs;
    };

    auto ld = [&](float (&buf)[3]) {
        __builtin_memcpy(&buf[0], xp, 12);
        xp += xst;
        sbar();
    };

    float x0[3], x1[3], x2[3], x3[3], x4[3], x5[3], x6[3], x7[3];
    ld(x0); ld(x1); ld(x2); ld(x3); ld(x4); ld(x5); ld(x6); ld(x7);

#pragma unroll 1
    for (int s = 0; s < S_ - 8; s += 8) {
        step(x0, wp); wp += wst; ld(x0);
        step(x1, wp); wp += wst; ld(x1);
        step(x2, wp); wp += wst; ld(x2);
        step(x3, wp); wp += wst; ld(x3);
        step(x4, wp); wp += wst; ld(x4);
        step(x5, wp); wp += wst; ld(x5);
        step(x6, wp); wp += wst; ld(x6);
        step(x7, wp); wp += wst; ld(x7);
    }
    step(x0, wp); wp += wst;
    step(x1, wp); wp += wst;
    step(x2, wp); wp += wst;
    step(x3, wp); wp += wst;
    step(x4, wp); wp += wst;
    step(x5, wp); wp += wst;
    step(x6, wp); wp += wst;
    step(x7, wp);

    const size_t OUTE = (size_t)S_ * B_ * 10;
    float* hn = outbase + OUTE + ((size_t)dir * B_ + b) * 5;
    float* cn = hn + (size_t)4 * B_ * 5;
    if (st) { hn[uc] = hu_last; cn[uc] = cp * IT2E; }
}

// ------- Layer 1: ws planes -> out [S][B][10] f32, MITM, 5-lane groups -------
__global__ __launch_bounds__(64) __attribute__((amdgpu_waves_per_eu(1, 2)))
void lstm_layer1(
    const unsigned short* __restrict__ ws,
    const float* __restrict__ wih_f, const float* __restrict__ whh_f,
    const float* __restrict__ bih_f, const float* __restrict__ bhh_f,
    const float* __restrict__ wih_r, const float* __restrict__ whh_r,
    const float* __restrict__ bih_r, const float* __restrict__ bhh_r,
    float* __restrict__ outbase,
    unsigned short* __restrict__ gtemp)
{
    __shared__ unsigned short lt[TL * 60];      // 24960B -> 6 blocks/CU

    const int l64 = threadIdx.x & 63;
    const int bid = (int)blockIdx.x;
    const int bsw = xswz1366(bid);
    int r = l64 / 5; r = (r > 11) ? 11 : r;     // row-in-wave 0..11
    const int u   = l64 - r * 5;
    const int uc  = (u < 5) ? u : 4;
    const int rm  = (r < 6) ? r : r - 6;        // b-slot 0..5
    const int dir = (r >= 6) ? 1 : 0;           // rows 0-5 fwd, 6-11 bwd
    const int braw = bsw * 6 + rm;
    const bool valid = braw < B_;
    const int b   = valid ? braw : (B_ - 1);
    const bool st = valid && (u < 5);
    const bool lw = (l64 < 60);                 // stash lanes
    const int dir5 = dir * 5;
    const int pr  = dir ? (r - 6) : (r + 6);    // partner row in wave
    const int ps  = pr * 5 + uc;                // partner slot (row*5+unit), 0..59

    int bidx[5];
#pragma unroll
    for (int k = 0; k < 5; k++) bidx[k] = (r * 5 + k) * 4;

    const float* __restrict__ wih = dir ? wih_r : wih_f;
    const float* __restrict__ whh = dir ? whh_r : whh_f;
    const float* __restrict__ bih = dir ? bih_r : bih_f;
    const float* __restrict__ bhh = dir ? bhh_r : bhh_f;

    const int rows[4] = {uc, 5 + uc, 10 + uc, 15 + uc};
    const float scl[4] = {-L2E, -L2E, T2E, -L2E};
    // x-weights as fp16 pairs matching the two 12B plane rows:
    // fwd plane pairs p=0..2: (w0,w1)(w2,w3)(w4,0)
    // bwd plane pairs p=3..5: (w5,w6)(w7,w8)(w9,0)
    v2h WX[4][6];
    float WH[4][5], BS[4];
#pragma unroll
    for (int gi = 0; gi < 4; gi++) {
        const int rr = rows[gi]; const float sc = scl[gi];
#pragma unroll
        for (int p = 0; p < 6; p++) {
            const int i0 = (p < 3) ? 2 * p : 2 * p - 1;   // 0,2,4,5,7,9
            const bool pad = (p == 2) || (p == 5);
            const float w0 = wih[rr * 10 + i0] * sc;
            const float w1 = pad ? 0.f : wih[rr * 10 + i0 + 1] * sc;
            WX[gi][p] = (v2h){(_Float16)w0, (_Float16)w1};
        }
#pragma unroll
        for (int k = 0; k < 5; k++) WH[gi][k] = whh[rr * 5 + k] * sc;
        BS[gi] = (bih[rr] + bhh[rr]) * sc;
    }

    float h[5] = {0.f, 0.f, 0.f, 0.f, 0.f};
    float cp = 0.f, hu_last = 0.f;

    const int t0 = dir ? (S_ - 1) : 0;          // this row's s at t=0
    const unsigned short* rpf = ws + ((size_t)t0 * B_ + b) * 6;
    const unsigned short* rpb = rpf + (size_t)S_ * B_ * 6;
    // out pointer starts at the first row phase 2 writes:
    // fwd: s = 256 (t=256); bwd: s = 255.
    float* op = outbase + ((size_t)(dir ? 255 : 256) * B_ + b) * 10;
    const ptrdiff_t rst = dir ? -(ptrdiff_t)6 * B_ : (ptrdiff_t)6 * B_;
    const ptrdiff_t ost = dir ? -(ptrdiff_t)10 * B_ : (ptrdiff_t)10 * B_;

    // spill: steps 208..255 -> rows 0..47 of gtemp; write slot = l64
    // (slot of (row,unit) == row*5+unit for rows<12), read slot = ps.
    unsigned short* gw = gtemp + (size_t)bid * 64 + l64;

    struct A4 { float a0, a1, a2, a3; };

    auto dots = [&](const v2h (&xin)[6]) -> A4 {
        A4 v;
        v.a0 = BS[0]; v.a1 = BS[1]; v.a2 = BS[2]; v.a3 = BS[3];
#pragma unroll
        for (int p = 0; p < 6; p++) {
            v.a0 = dot2h(xin[p], WX[0][p], v.a0);
            v.a1 = dot2h(xin[p], WX[1][p], v.a1);
            v.a2 = dot2h(xin[p], WX[2][p], v.a2);
            v.a3 = dot2h(xin[p], WX[3][p], v.a3);
        }
        return v;
    };

    auto cell = [&](A4 v) -> float {
#pragma unroll
        for (int k = 0; k < 5; k++) {
            v.a0 = fmaf(WH[0][k], h[k], v.a0);
            v.a1 = fmaf(WH[1][k], h[k], v.a1);
            v.a2 = fmaf(WH[2][k], h[k], v.a2);
            v.a3 = fmaf(WH[3][k], h[k], v.a3);
        }
        const float ig = rcp_(1.0f + exp2_(v.a0));
        const float fg = rcp_(1.0f + exp2_(v.a1));
        const float g2 = fmaf(-2.0f * T2E, rcp_(1.0f + exp2_(v.a2)), T2E);
        const float og = rcp_(1.0f + exp2_(v.a3));
        cp = fmaf(fg, cp, ig * g2);
        const float th = fmaf(-2.0f, rcp_(1.0f + exp2_(cp)), 1.0f);
        const float hu = og * th;
        hu_last = hu;
        return hu;
    };

    auto bcast = [&](float hu) {
#pragma unroll
        for (int k = 0; k < 5; k++) h[k] = bperm(bidx[k], hu);
    };

    auto ld = [&](v2h (&buf)[6]) {
        __builtin_memcpy(&buf[0], rpf, 12);
        __builtin_memcpy(&buf[3], rpb, 12);
        rpf += rst; rpb += rst;
        sbar();
    };

    // phase steps: dots -> ld(next) -> cell -> bcast -> stash/stores
    auto s1L = [&](v2h (&xb)[6], int t) {
        A4 a = dots(xb); ld(xb);
        const float hu = cell(a); bcast(hu);
        if (lw) lt[t * 60 + l64] = f2h(hu);
    };
    auto s1G = [&](v2h (&xb)[6]) {
        A4 a = dots(xb); ld(xb);
        const float hu = cell(a); bcast(hu);
        *gw = f2h(hu); gw += GSTR;
    };
    auto s2G = [&](v2h (&xb)[6], unsigned short pvs) {
        A4 a = dots(xb); ld(xb);
        const float pv = h2f(pvs);
        const float hu = cell(a); bcast(hu);
        if (st) { op[dir5 + uc] = hu; op[5 - dir5 + uc] = pv; }
        op += ost;
    };
    // phase2b: partner value pipelined ONE step ahead in pvr (raw u16).
    // The ds_read for step t+1 is issued AFTER cell(t)'s lgkm-drain
    // point, so the bperm wait never has to drain a fresh LDS read.
    unsigned short pvr = 0;
    auto s2L = [&](v2h (&xb)[6], int t) {
        A4 a = dots(xb); ld(xb);
        const float hu = cell(a);
        const float pv = h2f(pvr);              // loaded last step
        int ni = 510 - t; ni = (ni < 0) ? 0 : ni;
        pvr = lt[ni * 60 + ps];                 // next step's partner
        bcast(hu);
        if (st) { op[dir5 + uc] = hu; op[5 - dir5 + uc] = pv; }
        op += ost;
    };
    auto s2Ln = [&](v2h (&xb)[6], int t) {      // tail: no x load
        A4 a = dots(xb);
        const float hu = cell(a);
        const float pv = h2f(pvr);
        int ni = 510 - t; ni = (ni < 0) ? 0 : ni;
        pvr = lt[ni * 60 + ps];
        bcast(hu);
        if (st) { op[dir5 + uc] = hu; op[5 - dir5 + uc] = pv; }
        op += ost;
    };

    v2h x0[6], x1[6], x2[6], x3[6], x4[6], x5[6], x6[6], x7[6];
    ld(x0); ld(x1); ld(x2); ld(x3); ld(x4); ld(x5); ld(x6); ld(x7);  // t=0..7

    // phi1a: t = 0..207 (LDS stash), loads 8..215
#pragma unroll 1
    for (int t = 0; t < TL; t += 8) {
        s1L(x0, t + 0); s1L(x1, t + 1); s1L(x2, t + 2); s1L(x3, t + 3);
        s1L(x4, t + 4); s1L(x5, t + 5); s1L(x6, t + 6); s1L(x7, t + 7);
    }
    // phi1b: t = 208..255 (global stash, rows 0..47), loads 216..263
#pragma unroll 1
    for (int t = TL; t < 256; t += 8) {
        s1G(x0); s1G(x1); s1G(x2); s1G(x3);
        s1G(x4); s1G(x5); s1G(x6); s1G(x7);
    }
    // drain: spill row 47 (written t=255) is read at t=256 by this wave.
    asm volatile("s_waitcnt vmcnt(0)" ::: "memory");
    // partner ring, depth 4: at step t (256..303) partner = spill row 303-t.
    const unsigned short* gb = gtemp + (size_t)bid * 64 + ps;
    unsigned short q0 = gb[(size_t)47 * GSTR];
    unsigned short q1 = gb[(size_t)46 * GSTR];
    unsigned short q2 = gb[(size_t)45 * GSTR];
    unsigned short q3 = gb[(size_t)44 * GSTR];
    const unsigned short* grq = gb + (size_t)43 * GSTR;
    // phi2a: t = 256..303 (partner from spill ring), loads 264..311;
    // last 4 ring reloads hit the 4 guard rows below gtemp (unused).
#pragma unroll 1
    for (int t = 256; t < 304; t += 8) {
        s2G(x0, q0); q0 = *grq; grq -= GSTR;
        s2G(x1, q1); q1 = *grq; grq -= GSTR;
        s2G(x2, q2); q2 = *grq; grq -= GSTR;
        s2G(x3, q3); q3 = *grq; grq -= GSTR;
        s2G(x4, q0); q0 = *grq; grq -= GSTR;
        s2G(x5, q1); q1 = *grq; grq -= GSTR;
        s2G(x6, q2); q2 = *grq; grq -= GSTR;
        s2G(x7, q3); q3 = *grq; grq -= GSTR;
    }
    // prime the phase2b partner pipeline: step t=304 needs lt row 207.
    pvr = lt[207 * 60 + ps];
    // phi2b: t = 304..503 (partner from LDS, 1-step-ahead), loads 312..511
#pragma unroll 1
    for (int t = 304; t < 504; t += 8) {
        s2L(x0, t + 0); s2L(x1, t + 1); s2L(x2, t + 2); s2L(x3, t + 3);
        s2L(x4, t + 4); s2L(x5, t + 5); s2L(x6, t + 6); s2L(x7, t + 7);
    }
    // tail: t = 504..511, no more x loads
    s2Ln(x0, 504); s2Ln(x1, 505); s2Ln(x2, 506); s2Ln(x3, 507);
    s2Ln(x4, 508); s2Ln(x5, 509); s2Ln(x6, 510); s2Ln(x7, 511);

    const size_t OUTE = (size_t)S_ * B_ * 10;
    float* hn = outbase + OUTE + ((size_t)(2 + dir) * B_ + b) * 5;
    float* cn = hn + (size_t)4 * B_ * 5;
    if (st) { hn[uc] = hu_last; cn[uc] = cp * IT2E; }
}

extern "C" void kernel_launch(void* const* d_in, const int* in_sizes, int n_in,
                              void* d_out, int out_size, void* d_ws, size_t ws_size,
                              hipStream_t stream) {
    const float* x       = (const float*)d_in[0];
    const float* wih_l0  = (const float*)d_in[1];
    const float* whh_l0  = (const float*)d_in[2];
    const float* bih_l0  = (const float*)d_in[3];
    const float* bhh_l0  = (const float*)d_in[4];
    const float* wih_l0r = (const float*)d_in[5];
    const float* whh_l0r = (const float*)d_in[6];
    const float* bih_l0r = (const float*)d_in[7];
    const float* bhh_l0r = (const float*)d_in[8];
    const float* wih_l1  = (const float*)d_in[9];
    const float* whh_l1  = (const float*)d_in[10];
    const float* bih_l1  = (const float*)d_in[11];
    const float* bhh_l1  = (const float*)d_in[12];
    const float* wih_l1r = (const float*)d_in[13];
    const float* whh_l1r = (const float*)d_in[14];
    const float* bih_l1r = (const float*)d_in[15];
    const float* bhh_l1r = (const float*)d_in[16];

    float* out = (float*)d_out;
    unsigned short* ws = (unsigned short*)d_ws;   // 2 planes * S*B*12B = 100.7 MB
    // spill: 4 guard rows + 48 data rows, each 1366*64 shorts (~9.1 MB total)
    unsigned short* gtemp = ws + (size_t)2 * S_ * B_ * 6 + (size_t)4 * GSTR;

    // layer0: 16384 (dir,row) sequences, 12 per wave -> 1366 single-wave blocks
    dim3 grid0(1366), block(64);
    lstm_layer0<<<grid0, block, 0, stream>>>(x,
        wih_l0, whh_l0, bih_l0, bhh_l0,
        wih_l0r, whh_l0r, bih_l0r, bhh_l0r,
        ws, out);
    // layer1: 6 b-values x 2 dirs per wave -> 1366 blocks (12 rows/wave)
    dim3 grid1(GD1);
    lstm_layer1<<<grid1, block, 0, stream>>>(ws,
        wih_l1, whh_l1, bih_l1, bhh_l1,
        wih_l1r, whh_l1r, bih_l1r, bhh_l1r,
        out, gtemp);
}